// Round 1
// baseline (24.142 us; speedup 1.0000x reference)
//
#include <hip/hip_runtime.h>

// SimpleRPMGLoss: out = mean(smooth_l1(pred[:, :3], tgt[:, :3]))
//               + 100 * mean(acos(clip((trace(R(pred_euler)^T-elementwise R(tgt_euler)) - 1)/2)))
// B = 2,097,152 rows of 6 f32 each. Memory-bound streaming reduction (~100 MB read).

constexpr int   B_ROWS = 2097152;
constexpr int   NBLK   = 2048;        // ~8 blocks/CU on 256 CUs; grid-stride
constexpr int   TPB    = 256;
constexpr float ANGLE_WEIGHT = 100.0f;
constexpr float EPS_F        = 1e-7f;

__device__ inline float smooth_l1_term(float d) {
    float ad = fabsf(d);
    return ad < 1.0f ? 0.5f * d * d : ad - 0.5f;
}

__device__ inline void euler_xyz_mat(float a, float b, float c, float r[9]) {
    float sa, ca, sb, cb, sc, cc;
    __sincosf(a, &sa, &ca);
    __sincosf(b, &sb, &cb);
    __sincosf(c, &sc, &cc);
    r[0] = cb * cc;
    r[1] = cc * sa * sb - ca * sc;
    r[2] = sc * sa + ca * cc * sb;
    r[3] = cb * sc;
    r[4] = ca * cc + sa * sb * sc;
    r[5] = ca * sb * sc - cc * sa;
    r[6] = -sb;
    r[7] = cb * sa;
    r[8] = ca * cb;
}

__device__ inline void accum_row(float px, float py, float pz,
                                 float pa, float pb, float pc,
                                 float tx, float ty, float tz,
                                 float ta, float tb, float tc,
                                 float& trans_acc, float& rot_acc) {
    trans_acc += smooth_l1_term(px - tx) + smooth_l1_term(py - ty) + smooth_l1_term(pz - tz);
    float rp[9], rt[9];
    euler_xyz_mat(pa, pb, pc, rp);
    euler_xyz_mat(ta, tb, tc, rt);
    float tr = 0.0f;
#pragma unroll
    for (int i = 0; i < 9; ++i) tr = fmaf(rp[i], rt[i], tr);
    float cosang = fminf(fmaxf((tr - 1.0f) * 0.5f, -1.0f + EPS_F), 1.0f - EPS_F);
    rot_acc += acosf(cosang);
}

__device__ inline void block_reduce2(float& a, float& b, float2* out_slot) {
#pragma unroll
    for (int off = 32; off > 0; off >>= 1) {
        a += __shfl_down(a, off, 64);
        b += __shfl_down(b, off, 64);
    }
    __shared__ float sa[TPB / 64], sb[TPB / 64];
    const int wid  = threadIdx.x >> 6;
    const int lane = threadIdx.x & 63;
    if (lane == 0) { sa[wid] = a; sb[wid] = b; }
    __syncthreads();
    if (threadIdx.x == 0) {
        float ta = 0.0f, tb = 0.0f;
#pragma unroll
        for (int w = 0; w < TPB / 64; ++w) { ta += sa[w]; tb += sb[w]; }
        *out_slot = make_float2(ta, tb);
    }
}

__global__ __launch_bounds__(TPB) void rpmg_partial_kernel(const float* __restrict__ pred,
                                                           const float* __restrict__ tgt,
                                                           float2* __restrict__ partial) {
    const int tid     = blockIdx.x * TPB + threadIdx.x;
    const int nthread = gridDim.x * TPB;
    const int npairs  = B_ROWS / 2;

    float trans_acc = 0.0f, rot_acc = 0.0f;

    for (int p = tid; p < npairs; p += nthread) {
        // 2 rows = 12 floats = 48 bytes -> three 16B-aligned float4 loads each.
        const float4* pp = reinterpret_cast<const float4*>(pred + (size_t)p * 12);
        const float4* tp = reinterpret_cast<const float4*>(tgt  + (size_t)p * 12);
        float4 p0 = pp[0], p1 = pp[1], p2 = pp[2];
        float4 t0 = tp[0], t1 = tp[1], t2 = tp[2];

        // Row A: trans (p0.x,p0.y,p0.z), euler (p0.w,p1.x,p1.y)
        accum_row(p0.x, p0.y, p0.z, p0.w, p1.x, p1.y,
                  t0.x, t0.y, t0.z, t0.w, t1.x, t1.y,
                  trans_acc, rot_acc);
        // Row B: trans (p1.z,p1.w,p2.x), euler (p2.y,p2.z,p2.w)
        accum_row(p1.z, p1.w, p2.x, p2.y, p2.z, p2.w,
                  t1.z, t1.w, t2.x, t2.y, t2.z, t2.w,
                  trans_acc, rot_acc);
    }

    block_reduce2(trans_acc, rot_acc, &partial[blockIdx.x]);
}

__global__ __launch_bounds__(TPB) void rpmg_final_kernel(const float2* __restrict__ partial,
                                                         float* __restrict__ out) {
    float ta = 0.0f, tb = 0.0f;
    for (int i = threadIdx.x; i < NBLK; i += TPB) {
        float2 v = partial[i];
        ta += v.x;
        tb += v.y;
    }
#pragma unroll
    for (int off = 32; off > 0; off >>= 1) {
        ta += __shfl_down(ta, off, 64);
        tb += __shfl_down(tb, off, 64);
    }
    __shared__ float sa[TPB / 64], sb[TPB / 64];
    const int wid  = threadIdx.x >> 6;
    const int lane = threadIdx.x & 63;
    if (lane == 0) { sa[wid] = ta; sb[wid] = tb; }
    __syncthreads();
    if (threadIdx.x == 0) {
        float st = 0.0f, sr = 0.0f;
#pragma unroll
        for (int w = 0; w < TPB / 64; ++w) { st += sa[w]; sr += sb[w]; }
        const float trans_loss = st / (3.0f * (float)B_ROWS);
        const float rot_loss   = sr / (float)B_ROWS;
        out[0] = trans_loss + ANGLE_WEIGHT * rot_loss;
    }
}

extern "C" void kernel_launch(void* const* d_in, const int* in_sizes, int n_in,
                              void* d_out, int out_size, void* d_ws, size_t ws_size,
                              hipStream_t stream) {
    const float* pred = (const float*)d_in[0];
    const float* tgt  = (const float*)d_in[1];
    float*  out     = (float*)d_out;
    float2* partial = (float2*)d_ws;   // NBLK * 8 bytes = 16 KB scratch

    rpmg_partial_kernel<<<NBLK, TPB, 0, stream>>>(pred, tgt, partial);
    rpmg_final_kernel<<<1, TPB, 0, stream>>>(partial, out);
}